// Round 1
// 429.088 us; speedup vs baseline: 1.0421x; 1.0421x over previous
//
#include <hip/hip_runtime.h>

// MultiHeadedAttention: B=4, S=2048, H=16, D_MODEL=1024, D_K=64
// Softmax over the QUERY axis (per key-column normalization).
// Pipeline: wprep -> 3x(xprep, proj_gemm) -> colsum_vscale -> attnpv -> out_gemm
// R8: kill LDS bank conflicts in attnpv + colsum_vscale.
//     64B-row tiles can never be conflict-free (only 4 granule slots/row);
//     widen all hot LDS tiles to 128B rows and apply the 3-bit granule XOR
//     (g' = g ^ (row&7), m214 recipe). global_load_lds keeps a LINEAR LDS
//     dest; the inverse swizzle is baked into the per-lane GLOBAL source
//     address (both-sides-or-neither rule). P repacked to [32 qpair][64]
//     rows of 128B with the same XOR -> every ds_read_b128/ds_write_b64 is
//     2-lanes-per-bank (free).

#define DEV __device__ __forceinline__

typedef __bf16 bf16x8 __attribute__((ext_vector_type(8)));
typedef float  f32x4  __attribute__((ext_vector_type(4)));

DEV unsigned short f2bf(float f) {
    __bf16 h = (__bf16)f;
    return __builtin_bit_cast(unsigned short, h);
}

DEV bf16x8 ldfrag(const unsigned short* p) {
    return *reinterpret_cast<const bf16x8*>(p);
}

DEV float fast_exp2(float x) {
#if __has_builtin(__builtin_amdgcn_exp2f)
    return __builtin_amdgcn_exp2f(x);
#else
    return exp2f(x);
#endif
}

// async global->LDS, 16B per lane; LDS dst = wave-uniform base + lane*16
DEV void gld16(const unsigned short* g, unsigned short* l) {
    __builtin_amdgcn_global_load_lds(
        (__attribute__((address_space(1))) void*)g,
        (__attribute__((address_space(3))) void*)l, 16, 0, 0);
}

#define MFMA(a,b,c) __builtin_amdgcn_mfma_f32_16x16x32_bf16((a),(b),(c),0,0,0)

// score*1/sqrt(64) then exp -> exp2(score * log2(e)/8); folded into Qh.
#define QSCALE 0.18033688011112042f

// ---------------------------------------------------------------------------
// Weight prep: Wq/Wk/Wv [16,1024,64] f32 -> Wt[z][n=h*64+k][m] bf16 (B^T layout)
//              Wo [1024,1024] f32 -> bf16 (already [n][m])
// ---------------------------------------------------------------------------
__global__ __launch_bounds__(256) void wprep(const float* __restrict__ Wq,
                                             const float* __restrict__ Wk,
                                             const float* __restrict__ Wv,
                                             const float* __restrict__ Wo,
                                             unsigned short* __restrict__ Wt,
                                             unsigned short* __restrict__ Wot) {
    int idx = blockIdx.x * 256 + threadIdx.x;   // < 1024*1024
    int which = blockIdx.y;
    if (which == 3) { Wot[idx] = f2bf(Wo[idx]); return; }
    const float* W = (which == 0) ? Wq : (which == 1) ? Wk : Wv;
    int n = idx >> 10, m = idx & 1023;
    int h = n >> 6, k = n & 63;
    Wt[(size_t)which * 1048576 + idx] = f2bf(W[h * 65536 + m * 64 + k]);
}

// ---------------------------------------------------------------------------
// X f32 -> bf16 (one input of 8192x1024 per launch)
// ---------------------------------------------------------------------------
__global__ __launch_bounds__(256) void xprep(const float* __restrict__ X,
                                             unsigned short* __restrict__ Xb) {
    int idx = (blockIdx.x * 256 + threadIdx.x) * 4;
    float4 f = *(const float4*)&X[idx];
    ushort4 o;
    o.x = f2bf(f.x); o.y = f2bf(f.y); o.z = f2bf(f.z); o.w = f2bf(f.w);
    *(ushort4*)&Xb[idx] = o;
}

// ---------------------------------------------------------------------------
// Projection GEMM (m97-style): C[8192x1024] = Xb * Bt^T + bias
// z=0 -> O=Qh[b,h,s,k] (pre-scaled by QSCALE); z=1 -> O=Kh; z=2 -> Vt[b,h,k,s]
// ---------------------------------------------------------------------------
__global__ __launch_bounds__(256) void proj_gemm(
        const unsigned short* __restrict__ Xb, const unsigned short* __restrict__ Bt,
        const float* __restrict__ bias, unsigned short* __restrict__ O,
        unsigned short* __restrict__ Vt, int z) {
    const int tid = threadIdx.x;
    const int bm = blockIdx.x, bn = blockIdx.y;

    __shared__ __align__(16) unsigned short As[128 * 32];
    __shared__ __align__(16) unsigned short Bs[128 * 32];

    const int lane = tid & 63, wid = tid >> 6;
    const int l16 = lane & 15, quad = lane >> 4;
    const int wm = wid & 1, wn = wid >> 1;

    const unsigned short* ga =
        Xb + (size_t)(bm * 128 + wid * 32 + (lane >> 2)) * 1024 + (lane & 3) * 8;
    const unsigned short* gb =
        Bt + (size_t)(bn * 128 + wid * 32 + (lane >> 2)) * 1024 + (lane & 3) * 8;
    unsigned short* la = &As[wid * 32 * 32];
    unsigned short* lb = &Bs[wid * 32 * 32];

    f32x4 acc[4][4] = {};
    for (int kt = 0; kt < 32; ++kt) {
        __syncthreads();
        const int k0 = kt * 32;
        gld16(ga + k0, la);
        gld16(ga + k0 + 16 * 1024, la + 16 * 32);
        gld16(gb + k0, lb);
        gld16(gb + k0 + 16 * 1024, lb + 16 * 32);
        __syncthreads();
        bf16x8 af[4], bfr[4];
#pragma unroll
        for (int mi = 0; mi < 4; ++mi)
            af[mi] = ldfrag(&As[(wm * 64 + mi * 16 + l16) * 32 + quad * 8]);
#pragma unroll
        for (int ni = 0; ni < 4; ++ni)
            bfr[ni] = ldfrag(&Bs[(wn * 64 + ni * 16 + l16) * 32 + quad * 8]);
#pragma unroll
        for (int mi = 0; mi < 4; ++mi)
#pragma unroll
            for (int ni = 0; ni < 4; ++ni)
                acc[mi][ni] = MFMA(af[mi], bfr[ni], acc[mi][ni]);
    }

#pragma unroll
    for (int mi = 0; mi < 4; ++mi)
#pragma unroll
        for (int ni = 0; ni < 4; ++ni)
#pragma unroll
            for (int r = 0; r < 4; ++r) {
                int row = bm * 128 + wm * 64 + mi * 16 + quad * 4 + r;  // flat b*s
                int col = bn * 128 + wn * 64 + ni * 16 + l16;           // h*64+k
                float v = acc[mi][ni][r] + bias[col];
                if (z == 0) v *= QSCALE;
                int b = row >> 11, s = row & 2047;
                int h = col >> 6, k = col & 63;
                unsigned short o = f2bf(v);
                if (z == 2) {
                    Vt[(size_t)((b * 16 + h) * 64 + k) * 2048 + s] = o;
                } else {
                    O[(size_t)((b * 16 + h) * 2048 + s) * 64 + k] = o;
                }
            }
}

// ---------------------------------------------------------------------------
// Column softmax denominators + V scaling fused, double-buffered Q staging:
//   Dcol[s] = sum_q exp2(S[q,s]); then Vt[bh,k,s-range] *= 1/Dcol[s].
// R8: Qs rows widened to 128B ([128 q][64 k]) with granule-XOR (row&7);
//     inverse swizzle on the global source address; linear gld16 dest.
// ---------------------------------------------------------------------------
__global__ __launch_bounds__(256) void colsum_vscale(
        const unsigned short* __restrict__ Qh, const unsigned short* __restrict__ Kh,
        unsigned short* __restrict__ Vt) {
    const int tid = threadIdx.x;
    const int st = blockIdx.x, bh = blockIdx.y;
    const unsigned short* Qb = Qh + (size_t)bh * 2048 * 64;
    const unsigned short* Kb = Kh + (size_t)bh * 2048 * 64;

    __shared__ __align__(16) unsigned short Qs[2][128 * 64];  // [buf][q*64+swz(k)]
    __shared__ float Dtmp[2][128];
    __shared__ float Dsh[128];

    const int lane = tid & 63, wid = tid >> 6;
    const int l16 = lane & 15, quad = lane >> 4;
    const int wm = wid & 1, wn = wid >> 1;
    const int l7 = l16 & 7;

    // K B-frags for this wave's 64 s-columns, register resident
    bf16x8 kf[2][4];
#pragma unroll
    for (int ks = 0; ks < 2; ++ks)
#pragma unroll
        for (int ni = 0; ni < 4; ++ni)
            kf[ks][ni] = ldfrag(&Kb[(size_t)(st * 128 + wn * 64 + ni * 16 + l16) * 64 +
                                    ks * 32 + quad * 8]);

    // staging source: row = wid*32 + gi*8 + (lane>>3); k-granule inverse-swizzled
    const unsigned short* gq = Qb + (size_t)(wid * 32 + (lane >> 3)) * 64 +
                               ((lane & 7) ^ (lane >> 3)) * 8;

    // prologue: stage tile 0 into buf 0 (4 calls x 8 rows x 128B per wave)
#pragma unroll
    for (int gi = 0; gi < 4; ++gi)
        gld16(gq + (size_t)gi * 8 * 64, &Qs[0][(wid * 32 + gi * 8) * 64]);

    float psum[4] = {0.f, 0.f, 0.f, 0.f};
    for (int it = 0; it < 16; ++it) {
        const int buf = it & 1;
        __syncthreads();   // tile `it` staged (vmcnt drain); buf^1 reads done
        if (it < 15) {
            const size_t q1 = (size_t)(it + 1) * 128;
#pragma unroll
            for (int gi = 0; gi < 4; ++gi)
                gld16(gq + (q1 + gi * 8) * 64, &Qs[buf ^ 1][(wid * 32 + gi * 8) * 64]);
        }
        f32x4 acc[4][4] = {};
#pragma unroll
        for (int ks = 0; ks < 2; ++ks) {
            bf16x8 af[4];
#pragma unroll
            for (int mi = 0; mi < 4; ++mi)
                af[mi] = ldfrag(&Qs[buf][(wm * 64 + mi * 16 + l16) * 64 +
                                         (((ks * 4 + quad) ^ l7) * 8)]);
#pragma unroll
            for (int mi = 0; mi < 4; ++mi)
#pragma unroll
                for (int ni = 0; ni < 4; ++ni)
                    acc[mi][ni] = MFMA(af[mi], kf[ks][ni], acc[mi][ni]);
        }
#pragma unroll
        for (int ni = 0; ni < 4; ++ni) {
            float d = 0.f;
#pragma unroll
            for (int mi = 0; mi < 4; ++mi)
#pragma unroll
                for (int r = 0; r < 4; ++r)
                    d += fast_exp2(acc[mi][ni][r]);
            psum[ni] += d;
        }
    }
#pragma unroll
    for (int ni = 0; ni < 4; ++ni) {           // reduce over quad groups (rows)
        float v = psum[ni];
        v += __shfl_xor(v, 16, 64);
        v += __shfl_xor(v, 32, 64);
        if (quad == 0) Dtmp[wm][wn * 64 + ni * 16 + l16] = v;
    }
    __syncthreads();
    if (tid < 128) Dsh[tid] = 1.0f / (Dtmp[0][tid] + Dtmp[1][tid]);
    __syncthreads();

    // scale V in place: rows k=tid>>2 (64), s-chunk c=tid&3 (32 each)
    const int k = tid >> 2, c = tid & 3;
    unsigned short* vrow = Vt + ((size_t)bh * 64 + k) * 2048 + st * 128 + c * 32;
#pragma unroll
    for (int j = 0; j < 4; ++j) {
        bf16x8 v = *(const bf16x8*)&vrow[j * 8];
        bf16x8 o;
#pragma unroll
        for (int e = 0; e < 8; ++e)
            o[e] = (__bf16)((float)v[e] * Dsh[c * 32 + j * 8 + e]);
        *(bf16x8*)&vrow[j * 8] = o;
    }
}

// ---------------------------------------------------------------------------
// attn*V, s-split phase2 (P fully intra-wave):
//   wave (wq, ws): phase1: S^T[s in ws-half32][q in wq-half64] = K.Q^T
//                  exp2 -> per-wave P LDS region; phase2: partial
//                  ctx^T[k all 64][q 64] over own s-half.
// R8: Ks [buf][64 s][64 k], Vs [buf][64 k][64 s] -- 128B rows + granule-XOR
//     (row&7); staging sources inverse-swizzled per lane, LDS dest linear.
//     P repacked [32 qpair][64 slot] (slot=(q&1)*32+s), 128B rows, same XOR.
//     All hot ds_read_b128 / ds_write_b64 are now 2-lanes-per-bank (free).
// ---------------------------------------------------------------------------
__global__ __launch_bounds__(256) void attnpv(const unsigned short* __restrict__ Qh,
                                              const unsigned short* __restrict__ Kh,
                                              const unsigned short* __restrict__ Vn,
                                              unsigned short* __restrict__ Ctx) {
    const int tid = threadIdx.x;
    const int qt = blockIdx.x, bh = blockIdx.y;
    const int b = bh >> 4, h = bh & 15;
    const unsigned short* Qb = Qh + (size_t)bh * 2048 * 64;
    const unsigned short* Kb = Kh + (size_t)bh * 2048 * 64;
    const unsigned short* Vb = Vn + (size_t)bh * 64 * 2048;

    __shared__ __align__(16) unsigned char smem[49152];
    unsigned short* Ks = (unsigned short*)smem;             // [buf2][64 s][64 k] swz
    unsigned short* Vs = (unsigned short*)(smem + 16384);   // [buf2][64 k][64 s] swz
    unsigned short* Pw = (unsigned short*)(smem + 32768) + (tid >> 6) * 2048;
    // Pw: per-wave [32 qpair][64 slot], 128B rows, 16B-granule XOR by row&7

    const int lane = tid & 63, wid = tid >> 6;
    const int l16 = lane & 15, quad = lane >> 4;
    const int wq = wid & 1, ws = wid >> 1;
    const int l7 = l16 & 7;            // frag-row & 7 (rows = base16 + l16)
    const int ph = (l16 >> 1) & 7;     // P row & 7  (row = nj*8 + (l16>>1))
    const int pql = l16 & 1;           // q parity -> slot-half select

    // Q B-frags for this wave's 64 q columns, register resident
    bf16x8 qf[2][4];
#pragma unroll
    for (int ks = 0; ks < 2; ++ks)
#pragma unroll
        for (int nj = 0; nj < 4; ++nj)
            qf[ks][nj] = ldfrag(&Qb[(size_t)(qt * 128 + wq * 64 + nj * 16 + l16) * 64 +
                                    ks * 32 + quad * 8]);

    // staging: wid 0,1 -> K rows half*32..; wid 2,3 -> V k-rows half*32..
    // per gld16 call: 8 rows of 128B; lane -> (row=base+(lane>>3), g=lane&7);
    // global source granule = g ^ (row&7)  (inverse swizzle, LDS stays linear)
    const int half = wid & 1;
    const int sr8 = lane >> 3;
    const int sg = ((lane & 7) ^ sr8) * 8;
    const unsigned short* gk = Kb + (size_t)(half * 32 + sr8) * 64 + sg;
    const unsigned short* gv = Vb + (size_t)(half * 32 + sr8) * 2048 + sg;

    // prologue: stage K(0), V(0) into buf 0
    if (wid < 2) {
#pragma unroll
        for (int gi = 0; gi < 4; ++gi)
            gld16(gk + (size_t)gi * 8 * 64, &Ks[(half * 32 + gi * 8) * 64]);
    } else {
#pragma unroll
        for (int gi = 0; gi < 4; ++gi)
            gld16(gv + (size_t)gi * 8 * 2048, &Vs[(half * 32 + gi * 8) * 64]);
    }

    f32x4 cacc[4][4] = {};
    for (int it = 0; it < 32; ++it) {
        const int pb = it & 1;
        __syncthreads();   // K(it),V(it) staged in pb; pb^1 reads of it-1 done

        // prefetch K(it+1), V(it+1) into buf pb^1 (overlaps whole body)
        if (it < 31) {
            const size_t s1 = (size_t)(it + 1) * 64;
            if (wid < 2) {
#pragma unroll
                for (int gi = 0; gi < 4; ++gi)
                    gld16(gk + (s1 + gi * 8) * 64,
                          &Ks[(pb ^ 1) * 4096 + (half * 32 + gi * 8) * 64]);
            } else {
#pragma unroll
                for (int gi = 0; gi < 4; ++gi)
                    gld16(gv + (size_t)gi * 8 * 2048 + s1,
                          &Vs[(pb ^ 1) * 4096 + (half * 32 + gi * 8) * 64]);
            }
        }

        // phase 1: S^T (this wave: s = ws*32+[0,32), q = wq*64+[0,64))
        bf16x8 kf[2][2];
#pragma unroll
        for (int mi = 0; mi < 2; ++mi)
#pragma unroll
            for (int ks = 0; ks < 2; ++ks)
                kf[mi][ks] = ldfrag(&Ks[pb * 4096 + (ws * 32 + mi * 16 + l16) * 64 +
                                        (((ks * 4 + quad) ^ l7) * 8)]);
        f32x4 sacc[2][4] = {};
#pragma unroll
        for (int ks = 0; ks < 2; ++ks)
#pragma unroll
            for (int mi = 0; mi < 2; ++mi)
#pragma unroll
                for (int nj = 0; nj < 4; ++nj)
                    sacc[mi][nj] = MFMA(kf[mi][ks], qf[ks][nj], sacc[mi][nj]);

        // exp2 -> P write (b64; [qpair][slot] swizzled layout; intra-wave only)
        // value sacc[mi][nj][r]: q = nj*16+l16, s_local = mi*16+quad*4+r
        // row = q>>1, slot = (q&1)*32+s_local; granule G = slot>>3
#pragma unroll
        for (int mi = 0; mi < 2; ++mi) {
            const int G = pql * 4 + mi * 2 + (quad >> 1);
            const int po = ((G ^ ph) * 8) + (quad & 1) * 4;
#pragma unroll
            for (int nj = 0; nj < 4; ++nj) {
                ushort4 p;
                p.x = f2bf(fast_exp2(sacc[mi][nj][0]));
                p.y = f2bf(fast_exp2(sacc[mi][nj][1]));
                p.z = f2bf(fast_exp2(sacc[mi][nj][2]));
                p.w = f2bf(fast_exp2(sacc[mi][nj][3]));
                *(ushort4*)&Pw[(nj * 8 + (l16 >> 1)) * 64 + po] = p;
            }
        }

        // phase 2: partial ctx^T (k all 64, q 64, s = own ws-half)
        bf16x8 vf[4], pf[4];
#pragma unroll
        for (int mi = 0; mi < 4; ++mi)
            vf[mi] = ldfrag(&Vs[pb * 4096 + (mi * 16 + l16) * 64 +
                                (((ws * 4 + quad) ^ l7) * 8)]);
#pragma unroll
        for (int nj = 0; nj < 4; ++nj)
            pf[nj] = ldfrag(&Pw[(nj * 8 + (l16 >> 1)) * 64 +
                                (((pql * 4 + quad) ^ ph) * 8)]);
#pragma unroll
        for (int mi = 0; mi < 4; ++mi)
#pragma unroll
            for (int nj = 0; nj < 4; ++nj)
                cacc[mi][nj] = MFMA(vf[mi], pf[nj], cacc[mi][nj]);
    }

    // cross-wave reduce: cacc(wq, ws=0) += cacc(wq, ws=1), then store
    __syncthreads();
    f32x4* Red = (f32x4*)smem;   // [wq][16][64] = 32KB, aliases Ks/Vs
    if (ws == 1) {
#pragma unroll
        for (int mi = 0; mi < 4; ++mi)
#pragma unroll
            for (int nj = 0; nj < 4; ++nj)
                Red[(wq * 16 + mi * 4 + nj) * 64 + lane] = cacc[mi][nj];
    }
    __syncthreads();
    if (ws == 0) {
#pragma unroll
        for (int mi = 0; mi < 4; ++mi)
#pragma unroll
            for (int nj = 0; nj < 4; ++nj) {
                f32x4 t = Red[(wq * 16 + mi * 4 + nj) * 64 + lane];
                int q = qt * 128 + wq * 64 + nj * 16 + l16;
                int k = mi * 16 + quad * 4;
                ushort4 o;
                o.x = f2bf(cacc[mi][nj][0] + t[0]);
                o.y = f2bf(cacc[mi][nj][1] + t[1]);
                o.z = f2bf(cacc[mi][nj][2] + t[2]);
                o.w = f2bf(cacc[mi][nj][3] + t[3]);
                *(ushort4*)&Ctx[(size_t)(b * 2048 + q) * 1024 + h * 64 + k] = o;
            }
    }
}

// ---------------------------------------------------------------------------
// Output GEMM (m97-style): Out[8192x1024] f32 = Ctx(bf16) * Wo^T + bo
// ---------------------------------------------------------------------------
__global__ __launch_bounds__(256) void out_gemm(const unsigned short* __restrict__ A,
                                                const unsigned short* __restrict__ Bt,
                                                const float* __restrict__ bias,
                                                float* __restrict__ Out) {
    const int tid = threadIdx.x;
    const int bm = blockIdx.x, bn = blockIdx.y;

    __shared__ __align__(16) unsigned short As[128 * 32];
    __shared__ __align__(16) unsigned short Bs[128 * 32];

    const int lane = tid & 63, wid = tid >> 6;
    const int l16 = lane & 15, quad = lane >> 4;
    const int wm = wid & 1, wn = wid >> 1;

    const unsigned short* ga =
        A + (size_t)(bm * 128 + wid * 32 + (lane >> 2)) * 1024 + (lane & 3) * 8;
    const unsigned short* gb =
        Bt + (size_t)(bn * 128 + wid * 32 + (lane >> 2)) * 1024 + (lane & 3) * 8;
    unsigned short* la = &As[wid * 32 * 32];
    unsigned short* lb = &Bs[wid * 32 * 32];

    f32x4 acc[4][4] = {};
    for (int kt = 0; kt < 32; ++kt) {
        __syncthreads();
        const int k0 = kt * 32;
        gld16(ga + k0, la);
        gld16(ga + k0 + 16 * 1024, la + 16 * 32);
        gld16(gb + k0, lb);
        gld16(gb + k0 + 16 * 1024, lb + 16 * 32);
        __syncthreads();
        bf16x8 af[4], bfr[4];
#pragma unroll
        for (int mi = 0; mi < 4; ++mi)
            af[mi] = ldfrag(&As[(wm * 64 + mi * 16 + l16) * 32 + quad * 8]);
#pragma unroll
        for (int ni = 0; ni < 4; ++ni)
            bfr[ni] = ldfrag(&Bs[(wn * 64 + ni * 16 + l16) * 32 + quad * 8]);
#pragma unroll
        for (int mi = 0; mi < 4; ++mi)
#pragma unroll
            for (int ni = 0; ni < 4; ++ni)
                acc[mi][ni] = MFMA(af[mi], bfr[ni], acc[mi][ni]);
    }
#pragma unroll
    for (int mi = 0; mi < 4; ++mi)
#pragma unroll
        for (int ni = 0; ni < 4; ++ni)
#pragma unroll
            for (int r = 0; r < 4; ++r) {
                int row = bm * 128 + wm * 64 + mi * 16 + quad * 4 + r;
                int col = bn * 128 + wn * 64 + ni * 16 + l16;
                Out[(size_t)row * 1024 + col] = acc[mi][ni][r] + bias[col];
            }
}

// ---------------------------------------------------------------------------
extern "C" void kernel_launch(void* const* d_in, const int* in_sizes, int n_in,
                              void* d_out, int out_size, void* d_ws, size_t ws_size,
                              hipStream_t stream) {
    (void)in_sizes; (void)n_in; (void)out_size; (void)ws_size;
    const float* X[3] = {(const float*)d_in[0], (const float*)d_in[1],
                         (const float*)d_in[2]};
    const float* Wq = (const float*)d_in[3];
    const float* bq = (const float*)d_in[4];
    const float* Wk = (const float*)d_in[5];
    const float* bk = (const float*)d_in[6];
    const float* Wv = (const float*)d_in[7];
    const float* bv = (const float*)d_in[8];
    const float* Wo = (const float*)d_in[9];
    const float* bo = (const float*)d_in[10];
    const float* bias[3] = {bq, bk, bv};
    float* Out = (float*)d_out;

    char* ws = (char*)d_ws;
    const size_t MB = 1024 * 1024;
    unsigned short* Wt  = (unsigned short*)(ws);            // 6 MB  [3][1024][1024] bf16
    unsigned short* Wot = (unsigned short*)(ws + 6 * MB);   // 2 MB
    unsigned short* Qh  = (unsigned short*)(ws + 8 * MB);   // 16 MB [b,h,s,64] (pre-scaled)
    unsigned short* Kh  = (unsigned short*)(ws + 24 * MB);  // 16 MB
    unsigned short* Vt  = (unsigned short*)(ws + 40 * MB);  // 16 MB [b,h,64,s] -> scaled in place
    unsigned short* Ctx = (unsigned short*)(ws + 56 * MB);  // 16 MB [b*s,1024]
    unsigned short* Xb  = Ctx;                              // alias: Xb dead before Ctx live
    unsigned short* Oz[3] = {Qh, Kh, Qh /*unused for z=2*/};

    wprep<<<dim3(4096, 4), dim3(256), 0, stream>>>(Wq, Wk, Wv, Wo, Wt, Wot);
    for (int z = 0; z < 3; ++z) {
        xprep<<<dim3(8192), dim3(256), 0, stream>>>(X[z], Xb);
        proj_gemm<<<dim3(64, 8), dim3(256), 0, stream>>>(
            Xb, Wt + (size_t)z * 1048576, bias[z], Oz[z], Vt, z);
    }
    colsum_vscale<<<dim3(16, 64), dim3(256), 0, stream>>>(Qh, Kh, Vt);
    attnpv<<<dim3(16, 64), dim3(256), 0, stream>>>(Qh, Kh, Vt, Ctx);
    out_gemm<<<dim3(64, 8), dim3(256), 0, stream>>>(Ctx, Wot, bo, Out);
}